// Round 4
// baseline (36.928 us; speedup 1.0000x reference)
//
#include <hip/hip_runtime.h>
#include <math.h>

#define DIMD 16
#define HIDN 32
#define DIAG_MIN 0.316f
#define DIAG_MAX 3.16f
#define NTILES 9        // ceil(136 lower-tri rows / 16)
#define PSTRIDE 137     // odd stride -> conflict-free column access

typedef short bf16x8 __attribute__((ext_vector_type(8)));
typedef float f32x4  __attribute__((ext_vector_type(4)));

// fp32 -> bf16 (round-to-nearest-even), bit pattern as short
__device__ __forceinline__ short f2bf(float f) {
    unsigned u = __float_as_uint(f);
    unsigned r = (u + 0x7FFFu + ((u >> 16) & 1u)) >> 16;
    return (short)r;
}

// Block = 256 threads = 4 waves = 64 outputs (one m-chunk of one (b,n)).
// Phase A: wave w = M-tile w (16 outputs). Each lane computes h for output
//   (lane&15), k-chunk (lane>>4) -> A-fragment in registers. 9 compacted
//   lower-tri N-tiles of W2 -> B-fragments (fp32->bf16 in flight), b2 in
//   accumulator. One K=32 MFMA per tile: P[64][136] -> LDS.
// Phase B: thread (m = tid&63, kk = tid>>6 wave-uniform) combines 4 columns
//   k in {kk, kk+4, kk+8, kk+12}: diag softplus/clamp + y_k = sum dx_i L_ik,
//   dist^2 partials reduced via LDS.
__global__ __launch_bounds__(256, 4) void rm_kernel(
    const float* __restrict__ x1, const float* __restrict__ x2,
    const float* __restrict__ W1, const float* __restrict__ b1,
    const float* __restrict__ W2, const float* __restrict__ b2,
    float* __restrict__ out)
{
    __shared__ float Pl[64 * PSTRIDE];   // 35072 B: P = h @ W2tri^T (+b2)
    __shared__ float dxs[DIMD * 64];     // 4096 B: dx, [i][m]
    __shared__ float part[4 * 64];       // 1024 B: dist^2 partials

    const int tid  = threadIdx.x;
    const int lane = tid & 63;
    const int wid  = tid >> 6;           // M-tile
    const int blk  = blockIdx.x;         // 0..2047
    const int mc   = blk & 3;
    const int bn   = blk >> 2;
    const int b    = bn >> 8;

    const int arow = lane & 15;          // A row (output within M-tile)
    const int kgrp = lane >> 4;          // k-chunk 0..3
    const int m_loc = wid * 16 + arow;   // 0..63
    const int m     = mc * 64 + m_loc;

    // ---- mid + dx ----
    const float4* a4 = reinterpret_cast<const float4*>(x1 + bn * DIMD);
    const float4* c4 = reinterpret_cast<const float4*>(x2 + (b * 256 + m) * DIMD);
    float mid[DIMD];
    #pragma unroll
    for (int q = 0; q < 4; ++q) {
        float4 va = a4[q], vb = c4[q];
        mid[4*q+0] = (va.x + vb.x) * 0.5f;
        mid[4*q+1] = (va.y + vb.y) * 0.5f;
        mid[4*q+2] = (va.z + vb.z) * 0.5f;
        mid[4*q+3] = (va.w + vb.w) * 0.5f;
        if (kgrp == q) {                 // static q in address, predicated lane
            dxs[(4*q+0)*64 + m_loc] = vb.x - va.x;
            dxs[(4*q+1)*64 + m_loc] = vb.y - va.y;
            dxs[(4*q+2)*64 + m_loc] = vb.z - va.z;
            dxs[(4*q+3)*64 + m_loc] = vb.w - va.w;
        }
    }

    // ---- layer 1: this lane's 8 h-values = its A fragment ----
    bf16x8 A;
    #pragma unroll
    for (int jo = 0; jo < 8; ++jo) {
        const int j = kgrp * 8 + jo;
        const float* w1r = W1 + j * DIMD;
        float a0 = b1[j], a1 = 0.0f;
        #pragma unroll
        for (int i = 0; i < DIMD; i += 2) {
            a0 = fmaf(mid[i],     w1r[i],     a0);
            a1 = fmaf(mid[i + 1], w1r[i + 1], a1);
        }
        float acc = a0 + a1;
        A[jo] = f2bf(__fdividef(acc, 1.0f + __expf(-acc)));  // silu
    }

    // ---- layer 2 GEMM: 9 compact N-tiles, one K=32 MFMA each ----
    f32x4 acc[NTILES];
    #pragma unroll
    for (int t = 0; t < NTILES; ++t) {
        int rc = t * 16 + arow;
        rc = rc > 135 ? 135 : rc;        // pad cols duplicate rc=135 (benign)
        // rc -> (i,k) in lower triangle: i = row, k = col
        float s = __fsqrt_rn((float)(8 * rc + 1));
        int i = (int)((s - 1.0f) * 0.5f);
        i += ((((i + 1) * (i + 2)) >> 1) <= rc) ? 1 : 0;
        i -= (((i * (i + 1)) >> 1) > rc) ? 1 : 0;
        const int k = rc - ((i * (i + 1)) >> 1);
        const int r = i * DIMD + k;      // W2 row index

        const float* w2r = W2 + r * HIDN + kgrp * 8;
        bf16x8 Bf;
        #pragma unroll
        for (int jo = 0; jo < 8; ++jo) Bf[jo] = f2bf(w2r[jo]);

        const float b2v = b2[r];
        f32x4 c0 = {b2v, b2v, b2v, b2v};
        acc[t] = __builtin_amdgcn_mfma_f32_16x16x32_bf16(A, Bf, c0, 0, 0, 0);
    }

    // ---- write P to LDS: D row = kgrp*4+q (output), col = arow (rc) ----
    #pragma unroll
    for (int t = 0; t < NTILES; ++t) {
        const int rc = (t * 16 + arow) > 135 ? 135 : (t * 16 + arow);
        const int mrow = wid * 16 + kgrp * 4;
        #pragma unroll
        for (int q = 0; q < 4; ++q)
            Pl[(mrow + q) * PSTRIDE + rc] = acc[t][q];
    }

    __syncthreads();

    // ---- combine: thread (cm, kk); kk wave-uniform ----
    const int cm = tid & 63;
    const int kk = tid >> 6;
    const float* Pm = Pl + cm * PSTRIDE;

    float distp = 0.0f;
    #pragma unroll
    for (int qq = 0; qq < 4; ++qq) {
        const int k = kk + qq * 4;                  // wave-uniform
        const int trik = (k * (k + 1)) >> 1;
        // diagonal: P already has +b2; add identity 1, softplus, clamp
        float r = Pm[trik + k] + 1.0f;
        float sp = fmaxf(r, 0.0f) + log1pf(__expf(-fabsf(r)));
        float dg = fminf(fmaxf(sp, DIAG_MIN), DIAG_MAX);
        float y = dxs[k * 64 + cm] * dg;
        #pragma unroll 1
        for (int i = k + 1; i < DIMD; ++i)          // uniform trip count
            y = fmaf(dxs[i * 64 + cm], Pm[((i * (i + 1)) >> 1) + k], y);
        distp = fmaf(y, y, distp);
    }
    part[kk * 64 + cm] = distp;

    __syncthreads();

    if (tid < 64) {
        float d = part[tid] + part[64 + tid] + part[128 + tid] + part[192 + tid];
        out[bn * 256 + mc * 64 + tid] = __fsqrt_rn(fmaxf(d, 1e-6f));
    }
}

extern "C" void kernel_launch(void* const* d_in, const int* in_sizes, int n_in,
                              void* d_out, int out_size, void* d_ws, size_t ws_size,
                              hipStream_t stream) {
    const float* x1 = (const float*)d_in[0];
    const float* x2 = (const float*)d_in[1];
    const float* W1 = (const float*)d_in[2];
    const float* b1 = (const float*)d_in[3];
    const float* W2 = (const float*)d_in[4];
    const float* b2 = (const float*)d_in[5];
    float* out = (float*)d_out;

    rm_kernel<<<2048, 256, 0, stream>>>(x1, x2, W1, b1, W2, b2, out);
}

// Round 5
// 33.585 us; speedup vs baseline: 1.0995x; 1.0995x over previous
//
#include <hip/hip_runtime.h>
#include <math.h>

#define DIMD 16
#define HIDN 32
#define DIAG_MIN 0.316f
#define DIAG_MAX 3.16f
#define NTILES 9        // ceil(136 lower-tri rows / 16)
#define PSTRIDE 137     // stride%32=9, odd -> 64-lane column reads are 2-way (free)
#define TRI(i) (((i)*((i)+1))>>1)

typedef short bf16x8 __attribute__((ext_vector_type(8)));
typedef float f32x4  __attribute__((ext_vector_type(4)));

// fp32 -> bf16 (round-to-nearest-even)
__device__ __forceinline__ short f2bf(float f) {
    unsigned u = __float_as_uint(f);
    return (short)((u + 0x7FFFu + ((u >> 16) & 1u)) >> 16);
}

// One-block setup: compact the 136 lower-triangular rows of W2 into bf16
// w2c[rc][32] and b2 into b2c[rc] (rc = tri(i)+k). Removes per-block f2bf
// re-conversion (~300 VALU/thread x 2048 blocks) and the sqrt rc-decode
// from the hot kernel.
__global__ __launch_bounds__(256) void setup_kernel(
    const float* __restrict__ W2, const float* __restrict__ b2,
    short* __restrict__ w2c, float* __restrict__ b2c)
{
    const int t = threadIdx.x;
    for (int idx = t; idx < 136 * HIDN; idx += 256) {
        const int rc = idx >> 5;
        const int j  = idx & 31;
        int i = 0;
        while (TRI(i + 1) <= rc) ++i;
        const int k = rc - TRI(i);
        w2c[idx] = f2bf(W2[(i * DIMD + k) * HIDN + j]);
    }
    if (t < 136) {
        int i = 0;
        while (TRI(i + 1) <= t) ++i;
        const int k = t - TRI(i);
        b2c[t] = b2[i * DIMD + k];
    }
}

// Phase-B combine for wave-uniform KK: everything compile-time static ->
// all LDS reads batch (no serial load->fma chain, R3's regression cause).
template<int KK>
__device__ __forceinline__ float combine(const float* __restrict__ Pm,
                                         const float* __restrict__ dxr)
{
    float distp = 0.0f;
    #pragma unroll
    for (int qq = 0; qq < 4; ++qq) {
        const int k = KK + 4 * qq;
        float r = Pm[TRI(k) + k] + 1.0f;   // +identity bias (b2 already in P)
        float sp = fmaxf(r, 0.0f) + log1pf(__expf(-fabsf(r)));
        float dg = fminf(fmaxf(sp, DIAG_MIN), DIAG_MAX);
        float y = dxr[k] * dg;
        #pragma unroll
        for (int i = k + 1; i < DIMD; ++i)
            y = fmaf(dxr[i], Pm[TRI(i) + k], y);
        distp = fmaf(y, y, distp);
    }
    return distp;
}

// Block = 4 waves = 64 outputs (one m-chunk of one (b,n)).
// Phase A: wave = M-tile; lane (arow=lane&15, kgrp=lane>>4) computes h for
//   output arow, k-chunk kgrp -> A frag; 9 N-tiles of precompacted bf16 W2
//   -> 9 MFMAs (b2c in accumulator); P[64][136] -> LDS (stride 137).
// Phase B: thread (cm=tid&63, kk=tid>>6 uniform) -> switch(kk) into fully
//   static combine; cross-wave dist^2 reduce via part[].
__global__ __launch_bounds__(256, 4) void rm_kernel(
    const float* __restrict__ x1, const float* __restrict__ x2,
    const float* __restrict__ W1, const float* __restrict__ b1,
    const short* __restrict__ w2c, const float* __restrict__ b2c,
    float* __restrict__ out)
{
    __shared__ float Pl[64 * PSTRIDE];   // 35072 B
    __shared__ float dxs[DIMD * 64];     // 4096 B, [i][m]
    __shared__ float part[4 * 64];       // 1024 B   -> total 40192 B = 4 blk/CU

    const int tid  = threadIdx.x;
    const int lane = tid & 63;
    const int wid  = tid >> 6;
    const int blk  = blockIdx.x;
    const int mc   = blk & 3;
    const int bn   = blk >> 2;
    const int b    = bn >> 8;

    const int arow = lane & 15;
    const int kgrp = lane >> 4;
    const int m_loc = wid * 16 + arow;
    const int m     = mc * 64 + m_loc;

    // ---- mid + dx ----
    const float4* a4 = reinterpret_cast<const float4*>(x1 + bn * DIMD);
    const float4* c4 = reinterpret_cast<const float4*>(x2 + (b * 256 + m) * DIMD);
    float mid[DIMD];
    #pragma unroll
    for (int q = 0; q < 4; ++q) {
        float4 va = a4[q], vb = c4[q];
        mid[4*q+0] = (va.x + vb.x) * 0.5f;
        mid[4*q+1] = (va.y + vb.y) * 0.5f;
        mid[4*q+2] = (va.z + vb.z) * 0.5f;
        mid[4*q+3] = (va.w + vb.w) * 0.5f;
        if (kgrp == q) {
            dxs[(4*q+0)*64 + m_loc] = vb.x - va.x;
            dxs[(4*q+1)*64 + m_loc] = vb.y - va.y;
            dxs[(4*q+2)*64 + m_loc] = vb.z - va.z;
            dxs[(4*q+3)*64 + m_loc] = vb.w - va.w;
        }
    }

    // ---- layer 1: this lane's 8 h-values = its A fragment ----
    bf16x8 A;
    #pragma unroll
    for (int jo = 0; jo < 8; ++jo) {
        const int j = kgrp * 8 + jo;
        const float4* w1v = reinterpret_cast<const float4*>(W1 + j * DIMD);
        float4 w0 = w1v[0], w1r = w1v[1], w2r = w1v[2], w3r = w1v[3];
        float a0 = fmaf(mid[0], w0.x, b1[j]);
        float a1 = mid[1] * w0.y;
        a0 = fmaf(mid[2],  w0.z,  a0);  a1 = fmaf(mid[3],  w0.w,  a1);
        a0 = fmaf(mid[4],  w1r.x, a0);  a1 = fmaf(mid[5],  w1r.y, a1);
        a0 = fmaf(mid[6],  w1r.z, a0);  a1 = fmaf(mid[7],  w1r.w, a1);
        a0 = fmaf(mid[8],  w2r.x, a0);  a1 = fmaf(mid[9],  w2r.y, a1);
        a0 = fmaf(mid[10], w2r.z, a0);  a1 = fmaf(mid[11], w2r.w, a1);
        a0 = fmaf(mid[12], w3r.x, a0);  a1 = fmaf(mid[13], w3r.y, a1);
        a0 = fmaf(mid[14], w3r.z, a0);  a1 = fmaf(mid[15], w3r.w, a1);
        float acc = a0 + a1;
        A[jo] = f2bf(__fdividef(acc, 1.0f + __expf(-acc)));  // silu
    }

    // ---- layer 2: 9 MFMAs over precompacted bf16 W2 ----
    f32x4 acc[NTILES];
    #pragma unroll
    for (int t = 0; t < NTILES; ++t) {
        int rc = t * 16 + arow;
        rc = rc > 135 ? 135 : rc;        // pad cols duplicate rc=135 (benign)
        bf16x8 Bf = *reinterpret_cast<const bf16x8*>(w2c + rc * HIDN + kgrp * 8);
        const float b2v = b2c[rc];
        f32x4 c0 = {b2v, b2v, b2v, b2v};
        acc[t] = __builtin_amdgcn_mfma_f32_16x16x32_bf16(A, Bf, c0, 0, 0, 0);
    }

    // ---- write P to LDS: lane holds D[row=kgrp*4+q][col=rc] ----
    const int mrow = wid * 16 + kgrp * 4;
    #pragma unroll
    for (int t = 0; t < NTILES; ++t) {
        int rc = t * 16 + arow;
        rc = rc > 135 ? 135 : rc;        // duplicate writes carry equal values
        #pragma unroll
        for (int q = 0; q < 4; ++q)
            Pl[(mrow + q) * PSTRIDE + rc] = acc[t][q];
    }

    __syncthreads();

    // ---- phase B ----
    const int cm = tid & 63;
    const int kk = __builtin_amdgcn_readfirstlane(tid >> 6);  // wave-uniform
    const float* Pm = Pl + cm * PSTRIDE;

    float dxr[DIMD];
    #pragma unroll
    for (int i = 0; i < DIMD; ++i)
        dxr[i] = dxs[i * 64 + cm];

    float distp;
    switch (kk) {
        case 0:  distp = combine<0>(Pm, dxr); break;
        case 1:  distp = combine<1>(Pm, dxr); break;
        case 2:  distp = combine<2>(Pm, dxr); break;
        default: distp = combine<3>(Pm, dxr); break;
    }
    part[tid] = distp;

    __syncthreads();

    if (tid < 64) {
        float d = part[tid] + part[64 + tid] + part[128 + tid] + part[192 + tid];
        out[bn * 256 + mc * 64 + tid] = __fsqrt_rn(fmaxf(d, 1e-6f));
    }
}

extern "C" void kernel_launch(void* const* d_in, const int* in_sizes, int n_in,
                              void* d_out, int out_size, void* d_ws, size_t ws_size,
                              hipStream_t stream) {
    const float* x1 = (const float*)d_in[0];
    const float* x2 = (const float*)d_in[1];
    const float* W1 = (const float*)d_in[2];
    const float* b1 = (const float*)d_in[3];
    const float* W2 = (const float*)d_in[4];
    const float* b2 = (const float*)d_in[5];
    float* out = (float*)d_out;

    short* w2c = (short*)d_ws;                       // 136*32 bf16 = 8704 B
    float* b2c = (float*)((char*)d_ws + 8704);       // 136 f32

    setup_kernel<<<1, 256, 0, stream>>>(W2, b2, w2c, b2c);
    rm_kernel<<<2048, 256, 0, stream>>>(x1, x2, W1, b1, w2c, b2c, out);
}